// Round 8
// baseline (2035.519 us; speedup 1.0000x reference)
//
#include <hip/hip_runtime.h>
#include <cstdint>
#include <cstddef>

#define NN 50000
#define INDIM 32
#define HIDD 128
#define OUTD 10
#define KK 5
#define EK 400000
#define GG 500
#define CAP 32   // max node degree per slice; Poisson(8): P(any overflow)~6e-6
#define NT 782   // ceil(NN/64)

typedef __attribute__((ext_vector_type(4))) float float4v;
typedef unsigned short ushort;

// ---------- fused degree-count + capacity-CSR scatter (ushort col) ----------
__global__ void k_scatter(const int* __restrict__ srcA, const int* __restrict__ dstA,
                          int* __restrict__ cnt, ushort* __restrict__ col) {
    int e = blockIdx.x * blockDim.x + threadIdx.x;
    if (e >= KK * EK) return;
    int s = e / EK;
    int sv = srcA[e], dv = dstA[e];
    int pos = atomicAdd(&cnt[s * NN + dv], 1);
    if (pos < CAP) col[(size_t)(s * NN + dv) * CAP + pos] = (ushort)sv;
}

// dinv = 1/sqrt(deg+1); dinv2s = 1/((deg+1)*k)  (slice s is k=s+1 self-coef)
__global__ void k_dinv(const int* __restrict__ cnt, float* __restrict__ dinv,
                       float* __restrict__ dinv2s) {
    int i = blockIdx.x * blockDim.x + threadIdx.x;
    if (i >= KK * NN) return;
    int s = i / NN;
    float d = (float)(cnt[i] + 1);
    dinv[i]   = 1.0f / sqrtf(d);
    dinv2s[i] = 1.0f / (d * (float)(s + 1));
}

// ---------- weight transpose: in[m][j][c] -> out[m][c][j] ----------
__global__ void k_tr(const float* __restrict__ in, float* __restrict__ out,
                     int J, int C, int total) {
    int idx = blockIdx.x * blockDim.x + threadIdx.x;
    if (idx >= total) return;
    int jc = J * C;
    int m = idx / jc, rem = idx - m * jc;
    int j = rem / C, c = rem - j * C;
    out[m * jc + c * J + j] = in[idx];
}

// ---------- column-split gather: Y_sl = (S_s/k) X_{lp1-1-s},  s = s0+sl ------
// blockIdx: g(=&7, XCD-pinned colgroup of 16 cols) x tile(64 nodes) x sl.
// Each XCD streams a 3.2 MB column slice of X -> L2-resident, 1 line/edge.
// Half-wave = 1 node: 8 edge slots x 4 col-lanes (float4 each).
__global__ __launch_bounds__(256) void k_gather(const float* __restrict__ xl,
                                                const int* __restrict__ cnt,
                                                const ushort* __restrict__ col,
                                                const float* __restrict__ dinv,
                                                const float* __restrict__ dinv2s,
                                                int lp1, int s0,
                                                float* __restrict__ Y) {
    int b = blockIdx.x;
    int g = b & 7;
    int rest = b >> 3;
    int tile = rest % NT;
    int sl = rest / NT;
    int s = s0 + sl;
    int r0 = tile * 64;
    int sN = s * NN;
    float inv_k = 1.0f / (float)(s + 1);
    const float* X = xl + (size_t)(lp1 - 1 - s) * NN * HIDD;
    float* Ys = Y + (size_t)sl * NN * HIDD;

    int lane = threadIdx.x & 63, wv = threadIdx.x >> 6;
    int half = lane >> 5, ln = lane & 31;
    int eslot = ln >> 2, c4 = ln & 3;
    int gcol = g * 16 + c4 * 4;

#pragma unroll 1
    for (int pass = 0; pass < 8; ++pass) {
        int node = r0 + pass * 8 + wv * 2 + half;
        bool v = node < NN;
        int nc = v ? node : NN - 1;
        int cn = 0;
        if (v) { cn = cnt[sN + node]; cn = cn < CAP ? cn : CAP; }
        const ushort* cp = col + (size_t)(sN + nc) * CAP;
        float hd = v ? dinv[sN + node] * inv_k : 0.f;
        float sd = v ? dinv2s[sN + node] : 0.f;
        float4v a = {0.f, 0.f, 0.f, 0.f};

        int cm = cn;
        { int o = __shfl_xor(cm, 32); cm = cm > o ? cm : o; }
        for (int i = 0; i < cm; i += 8) {
            int t = i + eslot;
            int j = (t < cn) ? (int)cp[t] : nc;
            float w = (t < cn) ? dinv[sN + j] * hd : 0.f;
            float4v xv = *(const float4v*)(X + (size_t)j * HIDD + gcol);
            a += xv * w;
        }
        // reduce over the 8 edge slots (xor 4/8/16 stays within the half)
#pragma unroll
        for (int d = 4; d < 32; d <<= 1) {
            float4v o;
            o[0] = __shfl_xor(a[0], d);
            o[1] = __shfl_xor(a[1], d);
            o[2] = __shfl_xor(a[2], d);
            o[3] = __shfl_xor(a[3], d);
            a += o;
        }
        float4v xs = *(const float4v*)(X + (size_t)nc * HIDD + gcol);
        a += xs * sd;
        if (v && ln < 4)
            *(float4v*)(Ys + (size_t)node * HIDD + gcol) = a;
    }
}

// ---------- chunked layer GEMM: out (+)= sum_sl Y_sl @ Wt[cib+s0+sl] ---------
// first: init (add summed bias); else RMW-accumulate. last: relu.
__global__ __launch_bounds__(256) void k_lgemm(const float* __restrict__ Y,
                                               const float* __restrict__ Wt,
                                               const float* __restrict__ conv_b,
                                               int lp1, int s0, int chunk,
                                               int first, int last,
                                               float* __restrict__ out) {
    constexpr int LDA = HIDD + 4;
    __shared__ float At[64 * LDA];
    int tid = threadIdx.x;
    int r0 = blockIdx.x * 64;
    int tr = tid >> 4, tc = tid & 15, ra = tr * 4;
    int cib = (lp1 - 1) * lp1 / 2;

    float acc[4][8];
#pragma unroll
    for (int q = 0; q < 4; ++q)
#pragma unroll
        for (int u = 0; u < 8; ++u) acc[q][u] = 0.f;

    for (int sl = 0; sl < chunk; ++sl) {
        const float* Ys = Y + (size_t)sl * NN * HIDD;
        // stage 64x128 tile
#pragma unroll
        for (int t = 0; t < 8; ++t) {
            int f4 = tid + t * 256;
            int row = f4 >> 5, cc = (f4 & 31) * 4;
            float4v v4 = {0.f, 0.f, 0.f, 0.f};
            int gr = r0 + row;
            if (gr < NN) v4 = *(const float4v*)(Ys + (size_t)gr * HIDD + cc);
            *(float4v*)(At + row * LDA + cc) = v4;
        }
        __syncthreads();

        const float* wp = Wt + (size_t)(cib + s0 + sl) * HIDD * HIDD + tc * 8;
#pragma unroll 4
        for (int c = 0; c < HIDD; ++c) {
            float4v w0 = *(const float4v*)(wp + (size_t)c * HIDD);
            float4v w1 = *(const float4v*)(wp + (size_t)c * HIDD + 4);
            float a0 = At[(ra + 0) * LDA + c];
            float a1 = At[(ra + 1) * LDA + c];
            float a2 = At[(ra + 2) * LDA + c];
            float a3 = At[(ra + 3) * LDA + c];
#pragma unroll
            for (int u = 0; u < 4; ++u) {
                acc[0][u] += a0 * w0[u];  acc[0][u + 4] += a0 * w1[u];
                acc[1][u] += a1 * w0[u];  acc[1][u + 4] += a1 * w1[u];
                acc[2][u] += a2 * w0[u];  acc[2][u + 4] += a2 * w1[u];
                acc[3][u] += a3 * w0[u];  acc[3][u + 4] += a3 * w1[u];
            }
        }
        __syncthreads();
    }

    float bj[8];
#pragma unroll
    for (int u = 0; u < 8; ++u) bj[u] = 0.f;
    if (first) {   // summed bias over all k of this layer, added once
        for (int k = 1; k <= lp1; ++k) {
            const float* bp = conv_b + (size_t)(cib + k - 1) * HIDD + tc * 8;
            float inv_k = 1.0f / (float)k;
#pragma unroll
            for (int u = 0; u < 8; ++u) bj[u] += bp[u] * inv_k;
        }
    }
#pragma unroll
    for (int q = 0; q < 4; ++q) {
        int gr = r0 + ra + q;
        if (gr >= NN) continue;
        float* op = out + (size_t)gr * HIDD + tc * 8;
        float v[8];
#pragma unroll
        for (int u = 0; u < 8; ++u) v[u] = acc[q][u] + bj[u];
        if (!first) {
            float4v p0 = *(const float4v*)(op);
            float4v p1 = *(const float4v*)(op + 4);
#pragma unroll
            for (int u = 0; u < 4; ++u) { v[u] += p0[u]; v[u + 4] += p1[u]; }
        }
        if (last) {
#pragma unroll
            for (int u = 0; u < 8; ++u) v[u] = v[u] > 0.f ? v[u] : 0.f;
        }
        float4v o0 = {v[0], v[1], v[2], v[3]};
        float4v o1 = {v[4], v[5], v[6], v[7]};
        *(float4v*)(op) = o0;
        *(float4v*)(op + 4) = o1;
    }
}

// ---------- embedding GEMM (K=32): xl0 = x @ emb_W.T + emb_b ----------
__global__ __launch_bounds__(256) void k_emb(const float* __restrict__ A,
                                             const float* __restrict__ Wt,
                                             const float* __restrict__ bias,
                                             float* __restrict__ out) {
    constexpr int KD = INDIM, LDA = KD + 4;
    __shared__ float At[64 * LDA];
    int tid = threadIdx.x;
    int r0 = blockIdx.x * 64;

    constexpr int F4R = KD / 4;
    constexpr int PER = 64 * F4R / 256;
#pragma unroll
    for (int t = 0; t < PER; ++t) {
        int f4 = tid + t * 256;
        int row = f4 / F4R, c4 = (f4 - row * F4R) * 4;
        float4v v = {0.f, 0.f, 0.f, 0.f};
        int gr = r0 + row;
        if (gr < NN) v = *(const float4v*)(A + (size_t)gr * KD + c4);
        *(float4v*)(At + row * LDA + c4) = v;
    }
    __syncthreads();

    int tr = tid >> 4, tc = tid & 15;
    int ra = tr * 4;
    float acc[4][8];
#pragma unroll
    for (int q = 0; q < 4; ++q)
#pragma unroll
        for (int u = 0; u < 8; ++u) acc[q][u] = 0.f;

    const float* wp = Wt + tc * 8;
#pragma unroll
    for (int c = 0; c < KD; ++c) {
        float4v w0 = *(const float4v*)(wp + (size_t)c * HIDD);
        float4v w1 = *(const float4v*)(wp + (size_t)c * HIDD + 4);
        float a0 = At[(ra + 0) * LDA + c];
        float a1 = At[(ra + 1) * LDA + c];
        float a2 = At[(ra + 2) * LDA + c];
        float a3 = At[(ra + 3) * LDA + c];
#pragma unroll
        for (int u = 0; u < 4; ++u) {
            acc[0][u] += a0 * w0[u];  acc[0][u + 4] += a0 * w1[u];
            acc[1][u] += a1 * w0[u];  acc[1][u + 4] += a1 * w1[u];
            acc[2][u] += a2 * w0[u];  acc[2][u + 4] += a2 * w1[u];
            acc[3][u] += a3 * w0[u];  acc[3][u + 4] += a3 * w1[u];
        }
    }

#pragma unroll
    for (int q = 0; q < 4; ++q) {
        int gr = r0 + ra + q;
        if (gr >= NN) continue;
        float* op = out + (size_t)gr * HIDD + tc * 8;
        float4v o0, o1;
#pragma unroll
        for (int u = 0; u < 4; ++u) {
            o0[u] = acc[q][u] + bias[tc * 8 + u];
            o1[u] = acc[q][u + 4] + bias[tc * 8 + u + 4];
        }
        *(float4v*)(op) = o0;
        *(float4v*)(op + 4) = o1;
    }
}

// ---------- pooling (100 consecutive nodes/graph) + 2-layer MLP ----------
__global__ __launch_bounds__(256) void k_poolf(const float* __restrict__ h,
                                               const float* __restrict__ r1W,
                                               const float* __restrict__ r1b,
                                               const float* __restrict__ r2W,
                                               const float* __restrict__ r2b,
                                               float* __restrict__ out) {
    __shared__ float pooled[384];
    __shared__ float hid[192];
    int g = blockIdx.x, tid = threadIdx.x;
    if (tid < 128) {
        const float* hp = h + (size_t)g * 100 * HIDD + tid;
        float s = 0.f, m = -3.0e38f;
        for (int n = 0; n < 100; ++n) {
            float v = hp[(size_t)n * HIDD];
            s += v;
            m = fmaxf(m, v);
        }
        pooled[tid] = s;
        pooled[128 + tid] = m;
        pooled[256 + tid] = s * 0.01f;
    }
    __syncthreads();
    if (tid < 192) {
        float acc = r1b[tid];
        const float* w = r1W + (size_t)tid * 384;
        for (int c = 0; c < 384; ++c) acc += pooled[c] * w[c];
        hid[tid] = acc >= 0.f ? acc : 0.01f * acc;
    }
    __syncthreads();
    if (tid < OUTD) {
        float acc = r2b[tid];
        const float* w = r2W + (size_t)tid * 192;
        for (int c = 0; c < 192; ++c) acc += hid[c] * w[c];
        out[g * OUTD + tid] = acc;
    }
}

extern "C" void kernel_launch(void* const* d_in, const int* in_sizes, int n_in,
                              void* d_out, int out_size, void* d_ws, size_t ws_size,
                              hipStream_t stream) {
    const float* x      = (const float*)d_in[0];
    const int*   kei    = (const int*)d_in[1];
    const float* emb_W  = (const float*)d_in[4];
    const float* emb_b  = (const float*)d_in[5];
    const float* conv_W = (const float*)d_in[6];
    const float* conv_b = (const float*)d_in[7];
    const float* r1W    = (const float*)d_in[8];
    const float* r1b    = (const float*)d_in[9];
    const float* r2W    = (const float*)d_in[10];
    const float* r2b    = (const float*)d_in[11];

    const int* srcA = kei;            // row 0 of (2, K*E_K)
    const int* dstA = kei + KK * EK;  // row 1

    char* p = (char*)d_ws;
    auto take = [&](size_t bytes) -> void* {
        void* q = (void*)p;
        p += (bytes + 255) & ~(size_t)255;
        return q;
    };
    // total ~224.8 MB (<= proven-safe region + margin)
    int*    cnt    = (int*)   take((size_t)KK * NN * 4);        //  1.0 MB
    float*  dinv   = (float*) take((size_t)KK * NN * 4);        //  1.0 MB
    float*  dinv2s = (float*) take((size_t)KK * NN * 4);        //  1.0 MB
    ushort* col    = (ushort*)take((size_t)KK * NN * CAP * 2);  // 16.0 MB
    float*  Wt     = (float*) take((size_t)15 * HIDD * HIDD * 4); // 1.0 MB
    float*  embWt  = (float*) take((size_t)INDIM * HIDD * 4);   // 16 KB
    float*  xl     = (float*) take((size_t)6 * NN * HIDD * 4);  // 153.6 MB
    float*  Y      = (float*) take((size_t)2 * NN * HIDD * 4);  // 51.2 MB (2 slices)

    hipMemsetAsync(cnt, 0, (size_t)KK * NN * 4, stream);

    int etotal = KK * EK;
    k_scatter<<<(etotal + 255) / 256, 256, 0, stream>>>(srcA, dstA, cnt, col);
    k_dinv<<<(KK * NN + 255) / 256, 256, 0, stream>>>(cnt, dinv, dinv2s);

    k_tr<<<(15 * HIDD * HIDD + 255) / 256, 256, 0, stream>>>(conv_W, Wt, HIDD, HIDD,
                                                             15 * HIDD * HIDD);
    k_tr<<<(HIDD * INDIM + 255) / 256, 256, 0, stream>>>(emb_W, embWt, HIDD, INDIM,
                                                         HIDD * INDIM);

    k_emb<<<NT, 256, 0, stream>>>(x, embWt, emb_b, xl);

    for (int l = 0; l < 5; ++l) {
        int lp1 = l + 1;
        float* out = xl + (size_t)lp1 * NN * HIDD;
        int done = 0;
        while (done < lp1) {
            int chunk = (lp1 - done) < 2 ? (lp1 - done) : 2;
            k_gather<<<8 * NT * chunk, 256, 0, stream>>>(xl, cnt, col, dinv, dinv2s,
                                                         lp1, done, Y);
            int first = (done == 0) ? 1 : 0;
            int last  = (done + chunk == lp1) ? 1 : 0;
            k_lgemm<<<NT, 256, 0, stream>>>(Y, Wt, conv_b, lp1, done, chunk,
                                            first, last, out);
            done += chunk;
        }
    }

    k_poolf<<<GG, 256, 0, stream>>>(xl + (size_t)5 * NN * HIDD, r1W, r1b, r2W, r2b,
                                    (float*)d_out);
}